// Round 9
// baseline (803.637 us; speedup 1.0000x reference)
//
#include <hip/hip_runtime.h>
#include <hip/hip_fp16.h>

constexpr int Nn = 100000;
constexpr int Ne = 1600000;
constexpr float BN_EPS = 1e-5f;

constexpr int SCAN_TILE = 1024;                          // elements per block
constexpr int SCAN_NB = (Nn + SCAN_TILE - 1) / SCAN_TILE; // 98

constexpr float FIX_SCALE = 16777216.f;       // 2^24
constexpr float FIX_INV = 1.f / 16777216.f;

constexpr int NCOPY = 32;        // replicated stats slots (anti-contention)
constexpr int CSTRIDE = 512;     // floats per slot

typedef _Float16 f16x8 __attribute__((ext_vector_type(8)));
typedef float f32x4 __attribute__((ext_vector_type(4)));

// ---------- fused init: zero pk + stats_part, build Wcat/bcat for merged heads ----------

__global__ void init_kernel(int* __restrict__ pk2, float* __restrict__ part,
                            const float* __restrict__ W_mu, const float* __restrict__ W_lv,
                            const float* __restrict__ b_mu, const float* __restrict__ b_lv,
                            float* __restrict__ wcat, float* __restrict__ bcat) {
  int i = blockIdx.x * blockDim.x + threadIdx.x;
  if (i < 2 * Nn) pk2[i] = 0;
  if (i < NCOPY * CSTRIDE) part[i] = 0.f;
  if (i < 64 * 64) {
    int k = i >> 6, c = i & 63;
    wcat[i] = (c < 32) ? W_mu[k * 32 + c] : W_lv[k * 32 + (c - 32)];
  }
  if (i < 64) bcat[i] = (i < 32) ? b_mu[i] : b_lv[i - 32];
}

// fused: one u64 atomic per edge packs {cnt:1 << 40 | fix24(w)}; returned old count
// bits give this edge's slot within its node (atomic-free CSR fill later)
__global__ __launch_bounds__(256)
void deg_pack_kernel(const int* __restrict__ row, const float* __restrict__ w,
                     unsigned long long* __restrict__ pk,
                     unsigned short* __restrict__ slot) {
  int e = (blockIdx.x * blockDim.x + threadIdx.x) * 4;
  if (e + 4 <= Ne) {
    int4 r4 = *(const int4*)(row + e);
    float4 w4 = *(const float4*)(w + e);
    unsigned long long o0 = atomicAdd(&pk[r4.x], (1ULL << 40) | (unsigned long long)__float2uint_rn(w4.x * FIX_SCALE));
    unsigned long long o1 = atomicAdd(&pk[r4.y], (1ULL << 40) | (unsigned long long)__float2uint_rn(w4.y * FIX_SCALE));
    unsigned long long o2 = atomicAdd(&pk[r4.z], (1ULL << 40) | (unsigned long long)__float2uint_rn(w4.z * FIX_SCALE));
    unsigned long long o3 = atomicAdd(&pk[r4.w], (1ULL << 40) | (unsigned long long)__float2uint_rn(w4.w * FIX_SCALE));
    ushort4 s4;
    s4.x = (unsigned short)(o0 >> 40); s4.y = (unsigned short)(o1 >> 40);
    s4.z = (unsigned short)(o2 >> 40); s4.w = (unsigned short)(o3 >> 40);
    *(ushort4*)(slot + e) = s4;
  } else {
    for (int i = e; i < Ne; i++) {
      unsigned long long o = atomicAdd(&pk[row[i]], (1ULL << 40) | (unsigned long long)__float2uint_rn(w[i] * FIX_SCALE));
      slot[i] = (unsigned short)(o >> 40);
    }
  }
}

// ---------- multi-block exclusive scan over pk counts -> rowptr + dinv ----------

__global__ __launch_bounds__(256)
void scan_phase1(const unsigned long long* __restrict__ pk, int* __restrict__ bsum) {
  __shared__ int s[256];
  int b = blockIdx.x, tid = threadIdx.x;
  int base = b * SCAN_TILE + tid * 4;
  int t = 0;
#pragma unroll
  for (int i = 0; i < 4; i++) {
    int idx = base + i;
    if (idx < Nn) t += (int)(pk[idx] >> 40);
  }
  s[tid] = t;
  __syncthreads();
  for (int st = 128; st > 0; st >>= 1) {
    if (tid < st) s[tid] += s[tid + st];
    __syncthreads();
  }
  if (tid == 0) bsum[b] = s[0];
}

__global__ __launch_bounds__(128)
void scan_phase2(int* __restrict__ bsum) {  // in-place exclusive scan, SCAN_NB <= 128
  __shared__ int s[128];
  int tid = threadIdx.x;
  int v = (tid < SCAN_NB) ? bsum[tid] : 0;
  s[tid] = v;
  __syncthreads();
  for (int st = 1; st < 128; st <<= 1) {
    int u = (tid >= st) ? s[tid - st] : 0;
    __syncthreads();
    s[tid] += u;
    __syncthreads();
  }
  if (tid < SCAN_NB) bsum[tid] = s[tid] - v;  // exclusive prefix
}

__global__ __launch_bounds__(256)
void scan_phase3(const unsigned long long* __restrict__ pk, const int* __restrict__ bsum,
                 int* __restrict__ rowptr, float* __restrict__ dinv) {
  __shared__ int s[256];
  int b = blockIdx.x, tid = threadIdx.x;
  int base = b * SCAN_TILE + tid * 4;
  int vals[4];
  int t = 0;
#pragma unroll
  for (int i = 0; i < 4; i++) {
    int idx = base + i;
    if (idx < Nn) {
      unsigned long long v = pk[idx];
      vals[i] = (int)(v >> 40);
      float deg = (float)(v & ((1ULL << 40) - 1)) * FIX_INV + 1.0f;  // + self-loop
      dinv[idx] = rsqrtf(fmaxf(deg, 1e-12f));
    } else vals[i] = 0;
    t += vals[i];
  }
  s[tid] = t;
  __syncthreads();
  for (int st = 1; st < 256; st <<= 1) {
    int u = (tid >= st) ? s[tid - st] : 0;
    __syncthreads();
    s[tid] += u;
    __syncthreads();
  }
  int run = bsum[b] + s[tid] - t;  // exclusive prefix for this thread's 4 elems
#pragma unroll
  for (int i = 0; i < 4; i++) {
    int idx = base + i;
    if (idx < Nn) { rowptr[idx] = run; run += vals[i]; }
  }
  if (b == SCAN_NB - 1 && tid == 255) rowptr[Nn] = bsum[b] + s[255];
}

// CSR fill, atomic-free: pos = rowptr[r] + slot[e]; one 8B scattered store per edge
__global__ __launch_bounds__(256)
void csr_fill_kernel(const int* __restrict__ row, const int* __restrict__ col,
                     const float* __restrict__ w, const float* __restrict__ dinv,
                     const int* __restrict__ rowptr, const unsigned short* __restrict__ slot,
                     int2* __restrict__ edge_s) {
  int e = (blockIdx.x * blockDim.x + threadIdx.x) * 4;
  if (e + 4 <= Ne) {
    int4 r4 = *(const int4*)(row + e);
    int4 c4 = *(const int4*)(col + e);
    float4 w4 = *(const float4*)(w + e);
    ushort4 s4 = *(const ushort4*)(slot + e);
    edge_s[rowptr[r4.x] + s4.x] = make_int2(c4.x, __float_as_int(dinv[r4.x] * w4.x * dinv[c4.x]));
    edge_s[rowptr[r4.y] + s4.y] = make_int2(c4.y, __float_as_int(dinv[r4.y] * w4.y * dinv[c4.y]));
    edge_s[rowptr[r4.z] + s4.z] = make_int2(c4.z, __float_as_int(dinv[r4.z] * w4.z * dinv[c4.z]));
    edge_s[rowptr[r4.w] + s4.w] = make_int2(c4.w, __float_as_int(dinv[r4.w] * w4.w * dinv[c4.w]));
  } else {
    for (int i = e; i < Ne; i++) {
      int r = row[i], c = col[i];
      edge_s[rowptr[r] + slot[i]] = make_int2(c, __float_as_int(dinv[r] * w[i] * dinv[c]));
    }
  }
}

// ---------- MFMA f16 GEMM, BN templated (64 or 128): BM=128 BK=32, 4 waves ----------
// A from fp32 (A) or fp16 (A16). Optional input-BN folded from REPLICATED partials.
// Optional split fp32 output (C2: cols 0..31 -> C, 32..63 -> C2) for merged heads.
// C/D layout (m89-verified): col = lane&15, row = (lane>>4)*4 + reg.

template<int BNF>   // number of 16-wide n-fragments: 4 (BN=64) or 8 (BN=128)
__global__ __launch_bounds__(256)
void gemm_mfma_kernel(const float* __restrict__ A, const __half* __restrict__ A16,
                      const float* __restrict__ W,
                      const float* __restrict__ bias, float* __restrict__ C,
                      float* __restrict__ C2, __half* __restrict__ Ch,
                      const float* __restrict__ in_part, const float* __restrict__ in_g,
                      const float* __restrict__ in_beta, float* __restrict__ out_part,
                      int M, int K, int Nc, int relu) {
  constexpr int BM = 128, BK = 32, BN = BNF * 16;
  constexpr int LDA = 40;             // fp16 elems/row incl pad
  constexpr int TPC = 256 / BN;       // threads per W column (4 or 2)
  constexpr int WCHUNK = BK / TPC;    // k-elems per thread (8 or 16)
  __shared__ __half Asm[BM][LDA];
  __shared__ __half Wsm[BN][LDA];     // Wsm[col][k] (transposed tile)
  __shared__ float bnsc[256], bnsh[256];
  __shared__ float sred[2][4][BN];
  int t = threadIdx.x;
  int wid = t >> 6, lane = t & 63;
  int fr = lane & 15, fg = lane >> 4;
  int row0 = blockIdx.y * BM, col0 = blockIdx.x * BN;
  if (in_part) {
    for (int c = t; c < K; c += 256) {
      float s = 0.f, q = 0.f;
#pragma unroll 8
      for (int k = 0; k < NCOPY; k++) {
        s += in_part[k * CSTRIDE + c];
        q += in_part[k * CSTRIDE + K + c];
      }
      float m = s * (1.f / Nn);
      float var = q * (1.f / Nn) - m * m;
      float sc = rsqrtf(var + BN_EPS) * in_g[c];
      bnsc[c] = sc;
      bnsh[c] = in_beta[c] - m * sc;
    }
    __syncthreads();
  }
  f32x4 acc[2][BNF] = {};
  int ar = t >> 1;             // A stage: row 0..127
  int ac = (t & 1) * 16;       //          k-chunk 0 or 16
  int wc = t / TPC;            // W stage: col 0..BN-1
  int wk = (t % TPC) * WCHUNK; //          k start
  for (int k0 = 0; k0 < K; k0 += BK) {
    {
      int grow = row0 + ar;
      float v[16];
      if (grow < M) {
        if (A16) {
          union { uint4 u[2]; __half h[16]; } raw;
          const uint4* ap = (const uint4*)(A16 + (size_t)grow * K + k0 + ac);
          raw.u[0] = ap[0]; raw.u[1] = ap[1];
#pragma unroll
          for (int j = 0; j < 16; j++) v[j] = __half2float(raw.h[j]);
        } else {
          const float4* ap = (const float4*)(A + (size_t)grow * K + k0 + ac);
#pragma unroll
          for (int q = 0; q < 4; q++) {
            float4 a = ap[q];
            v[q * 4 + 0] = a.x; v[q * 4 + 1] = a.y;
            v[q * 4 + 2] = a.z; v[q * 4 + 3] = a.w;
          }
        }
        if (in_part) {
#pragma unroll
          for (int j = 0; j < 16; j++)
            v[j] = v[j] * bnsc[k0 + ac + j] + bnsh[k0 + ac + j];
        }
      } else {
#pragma unroll
        for (int j = 0; j < 16; j++) v[j] = 0.f;
      }
      union { __half2 h2[8]; uint4 u4[2]; } pk_;
#pragma unroll
      for (int j = 0; j < 8; j++) pk_.h2[j] = __floats2half2_rn(v[2 * j], v[2 * j + 1]);
      *(uint4*)&Asm[ar][ac] = pk_.u4[0];
      *(uint4*)&Asm[ar][ac + 8] = pk_.u4[1];
    }
    {
      int gc = col0 + wc;
#pragma unroll
      for (int g8 = 0; g8 < WCHUNK / 8; g8++) {
        union { __half2 h2[4]; uint4 u4; } wpk;
#pragma unroll
        for (int j = 0; j < 4; j++) {
          float w0 = W[(size_t)(k0 + wk + g8 * 8 + 2 * j) * Nc + gc];
          float w1 = W[(size_t)(k0 + wk + g8 * 8 + 2 * j + 1) * Nc + gc];
          wpk.h2[j] = __floats2half2_rn(w0, w1);
        }
        *(uint4*)&Wsm[wc][wk + g8 * 8] = wpk.u4;
      }
    }
    __syncthreads();
    {
      f16x8 a0 = *(const f16x8*)&Asm[wid * 32 + fr][fg * 8];
      f16x8 a1 = *(const f16x8*)&Asm[wid * 32 + 16 + fr][fg * 8];
#pragma unroll
      for (int ni = 0; ni < BNF; ni++) {
        f16x8 b = *(const f16x8*)&Wsm[ni * 16 + fr][fg * 8];
        acc[0][ni] = __builtin_amdgcn_mfma_f32_16x16x32_f16(a0, b, acc[0][ni], 0, 0, 0);
        acc[1][ni] = __builtin_amdgcn_mfma_f32_16x16x32_f16(a1, b, acc[1][ni], 0, 0, 0);
      }
    }
    __syncthreads();
  }
  // epilogue
  float csum[BNF], cssq[BNF];
  float bv[BNF];
#pragma unroll
  for (int ni = 0; ni < BNF; ni++) {
    csum[ni] = 0.f; cssq[ni] = 0.f;
    bv[ni] = bias ? bias[col0 + ni * 16 + fr] : 0.f;
  }
#pragma unroll
  for (int mi = 0; mi < 2; mi++) {
#pragma unroll
    for (int ni = 0; ni < BNF; ni++) {
      int col = col0 + ni * 16 + fr;
      f32x4 d = acc[mi][ni];
#pragma unroll
      for (int j = 0; j < 4; j++) {
        int r = row0 + wid * 32 + mi * 16 + fg * 4 + j;
        if (r >= M) continue;
        float vv = d[j] + bv[ni];
        if (relu) vv = fmaxf(vv, 0.f);
        if (out_part) { csum[ni] += vv; cssq[ni] += vv * vv; }
        if (Ch) Ch[(size_t)r * Nc + col] = __float2half(vv);
        else if (C2) {  // merged heads split: cols<32 -> C, else C2 (both [N,32])
          if (col < 32) C[(size_t)r * 32 + col] = vv;
          else          C2[(size_t)r * 32 + col - 32] = vv;
        } else {
          C[(size_t)r * Nc + col] = vv;
        }
      }
    }
  }
  if (out_part) {
#pragma unroll
    for (int ni = 0; ni < BNF; ni++) {
      csum[ni] += __shfl_xor(csum[ni], 16); csum[ni] += __shfl_xor(csum[ni], 32);
      cssq[ni] += __shfl_xor(cssq[ni], 16); cssq[ni] += __shfl_xor(cssq[ni], 32);
    }
    if (fg == 0) {
#pragma unroll
      for (int ni = 0; ni < BNF; ni++) {
        sred[0][wid][ni * 16 + fr] = csum[ni];
        sred[1][wid][ni * 16 + fr] = cssq[ni];
      }
    }
    __syncthreads();
    if (t < BN) {
      float s = sred[0][0][t] + sred[0][1][t] + sred[0][2][t] + sred[0][3][t];
      float q = sred[1][0][t] + sred[1][1][t] + sred[1][2][t] + sred[1][3][t];
      float* dst = out_part + (blockIdx.y & (NCOPY - 1)) * CSTRIDE;
      atomicAdd(&dst[col0 + t], s);
      atomicAdd(&dst[Nc + col0 + t], q);
    }
  }
}

// ---------- gather SpMM (fp16 features, fp32 accumulate) ----------

// 64-dim: 32 lanes per node (half2/lane), 2 nodes per wave, 8 loads in flight
__global__ __launch_bounds__(256)
void gather64_kernel(const __half* __restrict__ t, const int* __restrict__ rowptr,
                     const int2* __restrict__ edge_s,
                     const float* __restrict__ dinv, const float* __restrict__ bias,
                     float* __restrict__ out, __half* __restrict__ outh, int relu) {
  int sub = threadIdx.x >> 5;       // 8 sub-groups of 32 lanes
  int lane = threadIdx.x & 31;
  int node = blockIdx.x * 8 + sub;
  if (node >= Nn) return;
  int start = rowptr[node], end = rowptr[node + 1];
  float s = dinv[node];
  const __half2* tp = (const __half2*)t;  // row stride = 32 half2
  float2 ti = __half22float2(tp[(size_t)node * 32 + lane]);
  float ax = s * s * ti.x, ay = s * s * ti.y;
  for (int base = start; base < end; base += 32) {
    int m = end - base; if (m > 32) m = 32;
    int cv = 0; float nv = 0.f;
    if (lane < m) {
      int2 ev = edge_s[base + lane];
      cv = ev.x; nv = __int_as_float(ev.y);
    }
    int k = 0;
    for (; k + 8 <= m; k += 8) {
      int c0 = __shfl(cv, k + 0, 32), c1 = __shfl(cv, k + 1, 32);
      int c2 = __shfl(cv, k + 2, 32), c3 = __shfl(cv, k + 3, 32);
      int c4 = __shfl(cv, k + 4, 32), c5 = __shfl(cv, k + 5, 32);
      int c6 = __shfl(cv, k + 6, 32), c7 = __shfl(cv, k + 7, 32);
      float n0 = __shfl(nv, k + 0, 32), n1 = __shfl(nv, k + 1, 32);
      float n2 = __shfl(nv, k + 2, 32), n3 = __shfl(nv, k + 3, 32);
      float n4 = __shfl(nv, k + 4, 32), n5 = __shfl(nv, k + 5, 32);
      float n6 = __shfl(nv, k + 6, 32), n7 = __shfl(nv, k + 7, 32);
      float2 t0 = __half22float2(tp[(size_t)c0 * 32 + lane]);
      float2 t1 = __half22float2(tp[(size_t)c1 * 32 + lane]);
      float2 t2 = __half22float2(tp[(size_t)c2 * 32 + lane]);
      float2 t3 = __half22float2(tp[(size_t)c3 * 32 + lane]);
      float2 t4 = __half22float2(tp[(size_t)c4 * 32 + lane]);
      float2 t5 = __half22float2(tp[(size_t)c5 * 32 + lane]);
      float2 t6 = __half22float2(tp[(size_t)c6 * 32 + lane]);
      float2 t7 = __half22float2(tp[(size_t)c7 * 32 + lane]);
      ax += n0 * t0.x; ay += n0 * t0.y;  ax += n1 * t1.x; ay += n1 * t1.y;
      ax += n2 * t2.x; ay += n2 * t2.y;  ax += n3 * t3.x; ay += n3 * t3.y;
      ax += n4 * t4.x; ay += n4 * t4.y;  ax += n5 * t5.x; ay += n5 * t5.y;
      ax += n6 * t6.x; ay += n6 * t6.y;  ax += n7 * t7.x; ay += n7 * t7.y;
    }
    for (; k < m; k++) {
      int c = __shfl(cv, k, 32);
      float nm = __shfl(nv, k, 32);
      float2 tv = __half22float2(tp[(size_t)c * 32 + lane]);
      ax += nm * tv.x; ay += nm * tv.y;
    }
  }
  float2 bb = ((const float2*)bias)[lane];
  ax += bb.x; ay += bb.y;
  if (relu) { ax = fmaxf(ax, 0.f); ay = fmaxf(ay, 0.f); }
  if (outh) ((__half2*)outh)[(size_t)node * 32 + lane] = __floats2half2_rn(ax, ay);
  else      ((float2*)out)[(size_t)node * 32 + lane] = make_float2(ax, ay);
}

// 128-dim: 64 lanes per node (half2/lane), 8 loads in flight, fp16 out
__global__ __launch_bounds__(256)
void gather128_kernel(const __half* __restrict__ t, const int* __restrict__ rowptr,
                      const int2* __restrict__ edge_s,
                      const float* __restrict__ dinv, const float* __restrict__ bias,
                      __half* __restrict__ outh, int relu) {
  int wave = threadIdx.x >> 6;
  int lane = threadIdx.x & 63;
  int node = blockIdx.x * 4 + wave;
  if (node >= Nn) return;
  int start = rowptr[node], end = rowptr[node + 1];
  float s = dinv[node];
  const __half2* tp = (const __half2*)t;  // row stride = 64 half2
  float2 ti = __half22float2(tp[(size_t)node * 64 + lane]);
  float ax = s * s * ti.x, ay = s * s * ti.y;
  for (int base = start; base < end; base += 64) {
    int m = end - base; if (m > 64) m = 64;
    int cv = 0; float nv = 0.f;
    if (lane < m) {
      int2 ev = edge_s[base + lane];
      cv = ev.x; nv = __int_as_float(ev.y);
    }
    int k = 0;
    for (; k + 8 <= m; k += 8) {
      int c0 = __shfl(cv, k + 0), c1 = __shfl(cv, k + 1);
      int c2 = __shfl(cv, k + 2), c3 = __shfl(cv, k + 3);
      int c4 = __shfl(cv, k + 4), c5 = __shfl(cv, k + 5);
      int c6 = __shfl(cv, k + 6), c7 = __shfl(cv, k + 7);
      float n0 = __shfl(nv, k + 0), n1 = __shfl(nv, k + 1);
      float n2 = __shfl(nv, k + 2), n3 = __shfl(nv, k + 3);
      float n4 = __shfl(nv, k + 4), n5 = __shfl(nv, k + 5);
      float n6 = __shfl(nv, k + 6), n7 = __shfl(nv, k + 7);
      float2 t0 = __half22float2(tp[(size_t)c0 * 64 + lane]);
      float2 t1 = __half22float2(tp[(size_t)c1 * 64 + lane]);
      float2 t2 = __half22float2(tp[(size_t)c2 * 64 + lane]);
      float2 t3 = __half22float2(tp[(size_t)c3 * 64 + lane]);
      float2 t4 = __half22float2(tp[(size_t)c4 * 64 + lane]);
      float2 t5 = __half22float2(tp[(size_t)c5 * 64 + lane]);
      float2 t6 = __half22float2(tp[(size_t)c6 * 64 + lane]);
      float2 t7 = __half22float2(tp[(size_t)c7 * 64 + lane]);
      ax += n0 * t0.x; ay += n0 * t0.y;  ax += n1 * t1.x; ay += n1 * t1.y;
      ax += n2 * t2.x; ay += n2 * t2.y;  ax += n3 * t3.x; ay += n3 * t3.y;
      ax += n4 * t4.x; ay += n4 * t4.y;  ax += n5 * t5.x; ay += n5 * t5.y;
      ax += n6 * t6.x; ay += n6 * t6.y;  ax += n7 * t7.x; ay += n7 * t7.y;
    }
    for (; k < m; k++) {
      int c = __shfl(cv, k);
      float nm = __shfl(nv, k);
      float2 tv = __half22float2(tp[(size_t)c * 64 + lane]);
      ax += nm * tv.x; ay += nm * tv.y;
    }
  }
  float2 bb = ((const float2*)bias)[lane];
  ax += bb.x; ay += bb.y;
  if (relu) { ax = fmaxf(ax, 0.f); ay = fmaxf(ay, 0.f); }
  ((__half2*)outh)[(size_t)node * 64 + lane] = __floats2half2_rn(ax, ay);
}

// ---------- fused: mu-BN + z + Student-t q + lv-BN (all stats from partials) ----------

__global__ __launch_bounds__(256)
void q_bn_kernel(const float* __restrict__ mu_raw, const float* __restrict__ part,
                 const float* __restrict__ g_mu, const float* __restrict__ be_mu,
                 const float* __restrict__ g_lv, const float* __restrict__ be_lv,
                 const float* __restrict__ centers,
                 float* __restrict__ out_mu, float* __restrict__ out_z,
                 float* __restrict__ out_lv, float* __restrict__ q) {
  __shared__ float cs[50 * 32];
  __shared__ float cn[50];
  __shared__ float sc[32], sh[32], sc2[32], sh2[32];
  int tid = threadIdx.x;
  for (int i = tid; i < 50 * 32; i += 256) cs[i] = centers[i];
  if (tid < 32) {
    // merged-head stats layout: sums[0..63], sq[64..127]; mu = cols 0..31, lv = 32..63
    float s = 0.f, qq = 0.f, s2 = 0.f, q2 = 0.f;
#pragma unroll 8
    for (int k = 0; k < NCOPY; k++) {
      const float* p = part + k * CSTRIDE;
      s  += p[tid];       qq += p[64 + tid];
      s2 += p[32 + tid];  q2 += p[96 + tid];
    }
    float m = s * (1.f / Nn);
    float var = qq * (1.f / Nn) - m * m;
    float f = rsqrtf(var + BN_EPS) * g_mu[tid];
    sc[tid] = f; sh[tid] = be_mu[tid] - m * f;
    float m2 = s2 * (1.f / Nn);
    float var2 = q2 * (1.f / Nn) - m2 * m2;
    float f2 = rsqrtf(var2 + BN_EPS) * g_lv[tid];
    sc2[tid] = f2; sh2[tid] = be_lv[tid] - m2 * f2;
  }
  __syncthreads();
  if (tid < 50) {
    float s = 0.f;
    for (int j = 0; j < 32; j++) { float v = cs[tid * 32 + j]; s += v * v; }
    cn[tid] = s;
  }
  __syncthreads();
  int n = blockIdx.x * blockDim.x + tid;
  if (n >= Nn) return;
  // lv BN in-place
  {
    float4* lp = (float4*)(out_lv + (size_t)n * 32);
#pragma unroll
    for (int j = 0; j < 8; j++) {
      float4 v = lp[j];
      int c = j * 4;
      v.x = v.x * sc2[c + 0] + sh2[c + 0];
      v.y = v.y * sc2[c + 1] + sh2[c + 1];
      v.z = v.z * sc2[c + 2] + sh2[c + 2];
      v.w = v.w * sc2[c + 3] + sh2[c + 3];
      lp[j] = v;
    }
  }
  float zr[32];
  float zn = 0.f;
  const float4* zp = (const float4*)(mu_raw + (size_t)n * 32);
  float4* mo = (float4*)(out_mu + (size_t)n * 32);
  float4* zo = (float4*)(out_z + (size_t)n * 32);
#pragma unroll
  for (int j = 0; j < 8; j++) {
    float4 v = zp[j];
    int c = j * 4;
    v.x = v.x * sc[c + 0] + sh[c + 0];
    v.y = v.y * sc[c + 1] + sh[c + 1];
    v.z = v.z * sc[c + 2] + sh[c + 2];
    v.w = v.w * sc[c + 3] + sh[c + 3];
    mo[j] = v; zo[j] = v;
    zr[c + 0] = v.x; zr[c + 1] = v.y; zr[c + 2] = v.z; zr[c + 3] = v.w;
    zn += v.x * v.x + v.y * v.y + v.z * v.z + v.w * v.w;
  }
  float qs = 0.f;
  for (int k = 0; k < 50; k++) {
    float dot = 0.f;
#pragma unroll
    for (int j = 0; j < 32; j++) dot += zr[j] * cs[k * 32 + j];
    float d2 = fmaxf(zn + cn[k] - 2.f * dot, 0.f);
    qs += 1.f / (1.f + d2);
  }
  float inv = 1.f / qs;
  float* qo = q + (size_t)n * 50;
  for (int k = 0; k < 50; k++) {
    float dot = 0.f;
#pragma unroll
    for (int j = 0; j < 32; j++) dot += zr[j] * cs[k * 32 + j];
    float d2 = fmaxf(zn + cn[k] - 2.f * dot, 0.f);
    qo[k] = inv / (1.f + d2);
  }
}

// ---------- launch ----------

extern "C" void kernel_launch(void* const* d_in, const int* in_sizes, int n_in,
                              void* d_out, int out_size, void* d_ws, size_t ws_size,
                              hipStream_t stream) {
  const float* x     = (const float*)d_in[0];
  const int*   ei    = (const int*)d_in[1];
  const float* ew    = (const float*)d_in[2];
  const float* W_g1  = (const float*)d_in[3];
  const float* b_g1  = (const float*)d_in[4];
  const float* W_g2  = (const float*)d_in[5];
  const float* b_g2  = (const float*)d_in[6];
  const float* W_g3  = (const float*)d_in[7];
  const float* b_g3  = (const float*)d_in[8];
  const float* W_mu  = (const float*)d_in[9];
  const float* b_mu  = (const float*)d_in[10];
  const float* W_lv  = (const float*)d_in[11];
  const float* b_lv  = (const float*)d_in[12];
  const float* g_mu  = (const float*)d_in[13];
  const float* be_mu = (const float*)d_in[14];
  const float* g_lv  = (const float*)d_in[15];
  const float* be_lv = (const float*)d_in[16];
  const float* W_d1  = (const float*)d_in[17];
  const float* b_d1  = (const float*)d_in[18];
  const float* g_d1  = (const float*)d_in[19];
  const float* be_d1 = (const float*)d_in[20];
  const float* W_d2  = (const float*)d_in[21];
  const float* b_d2  = (const float*)d_in[22];
  const float* g_d2  = (const float*)d_in[23];
  const float* be_d2 = (const float*)d_in[24];
  const float* W_d3  = (const float*)d_in[25];
  const float* b_d3  = (const float*)d_in[26];
  const float* cent  = (const float*)d_in[27];

  const int* row = ei;
  const int* col = ei + Ne;

  float* out    = (float*)d_out;
  float* out_z  = out;
  float* out_mu = out + (size_t)Nn * 32;
  float* out_lv = out + (size_t)Nn * 64;
  float* out_xr = out + (size_t)Nn * 96;   // [N,256]
  float* out_q  = out + (size_t)Nn * 352;  // [N,50]

  // workspace: dinv[N] | bufB[N*128] | wcat[4096] | bcat[64] | stats_part[16K] |
  //            rowptr[N+1] | bsum[129] | edge_s[E int2]   (~64.9 MB)
  float* ws     = (float*)d_ws;
  float* dinv   = ws;
  float* bufB   = dinv + Nn;
  float* wcat   = bufB + (size_t)Nn * 128;
  float* bcat   = wcat + 4096;
  float* stats_part = bcat + 64;                        // NCOPY*CSTRIDE floats, in WS
  int*   rowptr = (int*)(stats_part + NCOPY * CSTRIDE);
  int*   bsum   = rowptr + Nn + 1;
  int2*  edge_s = (int2*)(bsum + 128 + 1);
  unsigned long long* pk = (unsigned long long*)bufB;   // aliased; dead before gather128 writes

  __half* bufB16 = (__half*)bufB;                       // gather128 out / d2 out [N,128] fp16
  __half* tA   = (__half*)out_xr;                       // L1 t [N,128] fp16; L3 t [N,64] fp16
  __half* tC   = (__half*)(out_xr + (size_t)Nn * 128);  // L2 t [N,64] fp16; later L3 gather out fp16
  __half* tD   = (__half*)(out_xr + (size_t)Nn * 192);  // gather64-L2 out / d1 out [N,64] fp16
  unsigned short* slot = (unsigned short*)out_q;        // [Ne] u16; dead before q write

  auto cdiv = [](long a, long b) { return (int)((a + b - 1) / b); };
  dim3 blk(256);

  init_kernel<<<cdiv(2L * Nn, 256), blk, 0, stream>>>(
      (int*)pk, stats_part, W_mu, W_lv, b_mu, b_lv, wcat, bcat);
  deg_pack_kernel<<<cdiv(Ne / 4, 256), blk, 0, stream>>>(row, ew, pk, slot);

  scan_phase1<<<SCAN_NB, blk, 0, stream>>>(pk, bsum);
  scan_phase2<<<1, 128, 0, stream>>>(bsum);
  scan_phase3<<<SCAN_NB, blk, 0, stream>>>(pk, bsum, rowptr, dinv);
  csr_fill_kernel<<<cdiv(Ne / 4, 256), blk, 0, stream>>>(row, col, ew, dinv, rowptr, slot, edge_s);

  int g128 = cdiv(Nn, 4);   // gather128: 4 nodes/block
  int g64  = cdiv(Nn, 8);   // gather64: 8 nodes/block
  int gy   = cdiv(Nn, 128); // MFMA rows

  // GCN layer 1: 256 -> 128 (MFMA BN=128, x read ONCE), aggregate+relu -> fp16
  gemm_mfma_kernel<8><<<dim3(1, gy), blk, 0, stream>>>(
      x, nullptr, W_g1, nullptr, nullptr, nullptr, tA,
      nullptr, nullptr, nullptr, nullptr, Nn, 256, 128, 0);
  gather128_kernel<<<g128, blk, 0, stream>>>(tA, rowptr, edge_s, dinv, b_g1, bufB16, 1);

  // GCN layer 2: 128 -> 64 (MFMA, fp16 A), aggregate+relu -> fp16
  gemm_mfma_kernel<4><<<dim3(1, gy), blk, 0, stream>>>(
      nullptr, bufB16, W_g2, nullptr, nullptr, nullptr, tC,
      nullptr, nullptr, nullptr, nullptr, Nn, 128, 64, 0);
  gather64_kernel<<<g64, blk, 0, stream>>>(tC, rowptr, edge_s, dinv, b_g2, nullptr, tD, 1);

  // GCN layer 3: 64 -> 64 (MFMA, fp16 A), aggregate -> fp16 (tC region reused)
  gemm_mfma_kernel<4><<<dim3(1, gy), blk, 0, stream>>>(
      nullptr, tD, W_g3, nullptr, nullptr, nullptr, tA,
      nullptr, nullptr, nullptr, nullptr, Nn, 64, 64, 0);
  gather64_kernel<<<g64, blk, 0, stream>>>(tA, rowptr, edge_s, dinv, b_g3, nullptr, tC, 0);

  // merged VAE heads: 64 -> 64 (MFMA, fp16 A; cols 0..31 = mu, 32..63 = lv), stats in epilogue
  gemm_mfma_kernel<4><<<dim3(1, gy), blk, 0, stream>>>(
      nullptr, tC, wcat, bcat, out_mu, out_lv, nullptr,
      nullptr, nullptr, nullptr, stats_part, Nn, 64, 64, 0);

  // fused mu-BN + z + q + lv-BN (stats folded from partials inline)
  q_bn_kernel<<<cdiv(Nn, 256), blk, 0, stream>>>(out_mu, stats_part, g_mu, be_mu, g_lv, be_lv,
                                                 cent, out_mu, out_z, out_lv, out_q);

  // decoder 32 -> 64 -> 128 -> 256 (MFMA) with BN folded from partials into A-loads
  gemm_mfma_kernel<4><<<dim3(1, gy), blk, 0, stream>>>(
      out_z, nullptr, W_d1, b_d1, nullptr, nullptr, tD,
      nullptr, nullptr, nullptr, stats_part + 128, Nn, 32, 64, 1);
  gemm_mfma_kernel<8><<<dim3(1, gy), blk, 0, stream>>>(
      nullptr, tD, W_d2, b_d2, nullptr, nullptr, bufB16,
      stats_part + 128, g_d1, be_d1, stats_part + 256, Nn, 64, 128, 1);
  gemm_mfma_kernel<8><<<dim3(2, gy), blk, 0, stream>>>(
      nullptr, bufB16, W_d3, b_d3, out_xr, nullptr, nullptr,
      stats_part + 256, g_d2, be_d2, nullptr, Nn, 128, 256, 0);
}

// Round 10
// 764.889 us; speedup vs baseline: 1.0507x; 1.0507x over previous
//
#include <hip/hip_runtime.h>
#include <hip/hip_fp16.h>

constexpr int Nn = 100000;
constexpr int Ne = 1600000;
constexpr float BN_EPS = 1e-5f;

constexpr int SCAN_TILE = 1024;                          // elements per block
constexpr int SCAN_NB = (Nn + SCAN_TILE - 1) / SCAN_TILE; // 98

constexpr float FIX_SCALE = 16777216.f;       // 2^24
constexpr float FIX_INV = 1.f / 16777216.f;

constexpr int NCOPY = 32;        // replicated stats slots (anti-contention)
constexpr int CSTRIDE = 512;     // floats per slot

typedef _Float16 f16x8 __attribute__((ext_vector_type(8)));
typedef float f32x4 __attribute__((ext_vector_type(4)));

// ---------- fused init: zero pk + stats_part, build Wcat/bcat for merged heads ----------

__global__ void init_kernel(int* __restrict__ pk2, float* __restrict__ part,
                            const float* __restrict__ W_mu, const float* __restrict__ W_lv,
                            const float* __restrict__ b_mu, const float* __restrict__ b_lv,
                            float* __restrict__ wcat, float* __restrict__ bcat) {
  int i = blockIdx.x * blockDim.x + threadIdx.x;
  if (i < 2 * Nn) pk2[i] = 0;
  if (i < NCOPY * CSTRIDE) part[i] = 0.f;
  if (i < 64 * 64) {
    int k = i >> 6, c = i & 63;
    wcat[i] = (c < 32) ? W_mu[k * 32 + c] : W_lv[k * 32 + (c - 32)];
  }
  if (i < 64) bcat[i] = (i < 32) ? b_mu[i] : b_lv[i - 32];
}

// fused: one u64 atomic per edge packs {cnt:1 << 40 | fix24(w)}; returned old count
// bits give this edge's slot within its node (atomic-free CSR fill later)
__global__ __launch_bounds__(256)
void deg_pack_kernel(const int* __restrict__ row, const float* __restrict__ w,
                     unsigned long long* __restrict__ pk,
                     unsigned short* __restrict__ slot) {
  int e = (blockIdx.x * blockDim.x + threadIdx.x) * 4;
  if (e + 4 <= Ne) {
    int4 r4 = *(const int4*)(row + e);
    float4 w4 = *(const float4*)(w + e);
    unsigned long long o0 = atomicAdd(&pk[r4.x], (1ULL << 40) | (unsigned long long)__float2uint_rn(w4.x * FIX_SCALE));
    unsigned long long o1 = atomicAdd(&pk[r4.y], (1ULL << 40) | (unsigned long long)__float2uint_rn(w4.y * FIX_SCALE));
    unsigned long long o2 = atomicAdd(&pk[r4.z], (1ULL << 40) | (unsigned long long)__float2uint_rn(w4.z * FIX_SCALE));
    unsigned long long o3 = atomicAdd(&pk[r4.w], (1ULL << 40) | (unsigned long long)__float2uint_rn(w4.w * FIX_SCALE));
    ushort4 s4;
    s4.x = (unsigned short)(o0 >> 40); s4.y = (unsigned short)(o1 >> 40);
    s4.z = (unsigned short)(o2 >> 40); s4.w = (unsigned short)(o3 >> 40);
    *(ushort4*)(slot + e) = s4;
  } else {
    for (int i = e; i < Ne; i++) {
      unsigned long long o = atomicAdd(&pk[row[i]], (1ULL << 40) | (unsigned long long)__float2uint_rn(w[i] * FIX_SCALE));
      slot[i] = (unsigned short)(o >> 40);
    }
  }
}

// ---------- multi-block exclusive scan over pk counts -> rowptr + dinv ----------

__global__ __launch_bounds__(256)
void scan_phase1(const unsigned long long* __restrict__ pk, int* __restrict__ bsum) {
  __shared__ int s[256];
  int b = blockIdx.x, tid = threadIdx.x;
  int base = b * SCAN_TILE + tid * 4;
  int t = 0;
#pragma unroll
  for (int i = 0; i < 4; i++) {
    int idx = base + i;
    if (idx < Nn) t += (int)(pk[idx] >> 40);
  }
  s[tid] = t;
  __syncthreads();
  for (int st = 128; st > 0; st >>= 1) {
    if (tid < st) s[tid] += s[tid + st];
    __syncthreads();
  }
  if (tid == 0) bsum[b] = s[0];
}

__global__ __launch_bounds__(128)
void scan_phase2(int* __restrict__ bsum) {  // in-place exclusive scan, SCAN_NB <= 128
  __shared__ int s[128];
  int tid = threadIdx.x;
  int v = (tid < SCAN_NB) ? bsum[tid] : 0;
  s[tid] = v;
  __syncthreads();
  for (int st = 1; st < 128; st <<= 1) {
    int u = (tid >= st) ? s[tid - st] : 0;
    __syncthreads();
    s[tid] += u;
    __syncthreads();
  }
  if (tid < SCAN_NB) bsum[tid] = s[tid] - v;  // exclusive prefix
}

__global__ __launch_bounds__(256)
void scan_phase3(const unsigned long long* __restrict__ pk, const int* __restrict__ bsum,
                 int* __restrict__ rowptr, float* __restrict__ dinv) {
  __shared__ int s[256];
  int b = blockIdx.x, tid = threadIdx.x;
  int base = b * SCAN_TILE + tid * 4;
  int vals[4];
  int t = 0;
#pragma unroll
  for (int i = 0; i < 4; i++) {
    int idx = base + i;
    if (idx < Nn) {
      unsigned long long v = pk[idx];
      vals[i] = (int)(v >> 40);
      float deg = (float)(v & ((1ULL << 40) - 1)) * FIX_INV + 1.0f;  // + self-loop
      dinv[idx] = rsqrtf(fmaxf(deg, 1e-12f));
    } else vals[i] = 0;
    t += vals[i];
  }
  s[tid] = t;
  __syncthreads();
  for (int st = 1; st < 256; st <<= 1) {
    int u = (tid >= st) ? s[tid - st] : 0;
    __syncthreads();
    s[tid] += u;
    __syncthreads();
  }
  int run = bsum[b] + s[tid] - t;  // exclusive prefix for this thread's 4 elems
#pragma unroll
  for (int i = 0; i < 4; i++) {
    int idx = base + i;
    if (idx < Nn) { rowptr[idx] = run; run += vals[i]; }
  }
  if (b == SCAN_NB - 1 && tid == 255) rowptr[Nn] = bsum[b] + s[255];
}

// CSR fill, atomic-free: pos = rowptr[r] + slot[e]; one 8B scattered store per edge
__global__ __launch_bounds__(256)
void csr_fill_kernel(const int* __restrict__ row, const int* __restrict__ col,
                     const float* __restrict__ w, const float* __restrict__ dinv,
                     const int* __restrict__ rowptr, const unsigned short* __restrict__ slot,
                     int2* __restrict__ edge_s) {
  int e = (blockIdx.x * blockDim.x + threadIdx.x) * 4;
  if (e + 4 <= Ne) {
    int4 r4 = *(const int4*)(row + e);
    int4 c4 = *(const int4*)(col + e);
    float4 w4 = *(const float4*)(w + e);
    ushort4 s4 = *(const ushort4*)(slot + e);
    edge_s[rowptr[r4.x] + s4.x] = make_int2(c4.x, __float_as_int(dinv[r4.x] * w4.x * dinv[c4.x]));
    edge_s[rowptr[r4.y] + s4.y] = make_int2(c4.y, __float_as_int(dinv[r4.y] * w4.y * dinv[c4.y]));
    edge_s[rowptr[r4.z] + s4.z] = make_int2(c4.z, __float_as_int(dinv[r4.z] * w4.z * dinv[c4.z]));
    edge_s[rowptr[r4.w] + s4.w] = make_int2(c4.w, __float_as_int(dinv[r4.w] * w4.w * dinv[c4.w]));
  } else {
    for (int i = e; i < Ne; i++) {
      int r = row[i], c = col[i];
      edge_s[rowptr[r] + slot[i]] = make_int2(c, __float_as_int(dinv[r] * w[i] * dinv[c]));
    }
  }
}

// ---------- FP32 tiled GEMM 64x64, merged mu/lv heads (split epilogue) ----------

__global__ __launch_bounds__(256)
void gemm_kernel(const float* __restrict__ A, const float* __restrict__ W,
                 const float* __restrict__ bias, float* __restrict__ C,
                 float* __restrict__ C2, float* __restrict__ out_part,
                 int M, int K, int Nc, int relu) {
  constexpr int BM = 64, BN = 64, BK = 16;
  __shared__ float As[BK][BM + 4];
  __shared__ float Ws[BK][BN];
  int t = threadIdx.x;
  int tx = t & 15, ty = t >> 4;
  int row0 = blockIdx.y * BM, col0 = blockIdx.x * BN;
  float acc[4][4] = {};
  for (int k0 = 0; k0 < K; k0 += BK) {
    {
      int r = t >> 2;
      int kq = (t & 3) << 2;
      int grow = row0 + r;
      float4 a = make_float4(0.f, 0.f, 0.f, 0.f);
      if (grow < M) a = *(const float4*)(A + (size_t)grow * K + (k0 + kq));
      As[kq + 0][r] = a.x; As[kq + 1][r] = a.y;
      As[kq + 2][r] = a.z; As[kq + 3][r] = a.w;
    }
    {
      int r = t >> 4;
      int c = (t & 15) << 2;
      int gc = col0 + c;
      float4 w4 = make_float4(0.f, 0.f, 0.f, 0.f);
      if (gc < Nc) w4 = *(const float4*)(W + (size_t)(k0 + r) * Nc + gc);
      Ws[r][c + 0] = w4.x; Ws[r][c + 1] = w4.y;
      Ws[r][c + 2] = w4.z; Ws[r][c + 3] = w4.w;
    }
    __syncthreads();
#pragma unroll
    for (int kk = 0; kk < BK; kk++) {
      float4 av = *(const float4*)&As[kk][ty << 2];
      float4 wv = *(const float4*)&Ws[kk][tx << 2];
      float a4[4] = {av.x, av.y, av.z, av.w};
      float w4[4] = {wv.x, wv.y, wv.z, wv.w};
#pragma unroll
      for (int i = 0; i < 4; i++)
#pragma unroll
        for (int j = 0; j < 4; j++)
          acc[i][j] += a4[i] * w4[j];
    }
    __syncthreads();
  }
  float cs[4] = {0.f, 0.f, 0.f, 0.f}, cq[4] = {0.f, 0.f, 0.f, 0.f};
#pragma unroll
  for (int i = 0; i < 4; i++) {
    int grow = row0 + (ty << 2) + i;
    if (grow >= M) continue;
#pragma unroll
    for (int j = 0; j < 4; j++) {
      int gc = col0 + (tx << 2) + j;
      if (gc >= Nc) continue;
      float vv = acc[i][j];
      if (bias) vv += bias[gc];
      if (relu) vv = fmaxf(vv, 0.f);
      if (out_part) { cs[j] += vv; cq[j] += vv * vv; }
      if (C2) {  // split: cols 0..31 -> C[r*32+gc], 32..63 -> C2[r*32+gc-32]
        if (gc < 32) C[(size_t)grow * 32 + gc] = vv;
        else         C2[(size_t)grow * 32 + gc - 32] = vv;
      } else {
        C[(size_t)grow * Nc + gc] = vv;
      }
    }
  }
  if (out_part) {
    int cbase = tx << 2;
#pragma unroll
    for (int j = 0; j < 4; j++) { As[ty][cbase + j] = cs[j]; Ws[ty][cbase + j] = cq[j]; }
    __syncthreads();
    for (int st = 8; st > 0; st >>= 1) {
      if (ty < st) {
#pragma unroll
        for (int j = 0; j < 4; j++) {
          As[ty][cbase + j] += As[ty + st][cbase + j];
          Ws[ty][cbase + j] += Ws[ty + st][cbase + j];
        }
      }
      __syncthreads();
    }
    if (ty == 0) {
      float* dst = out_part + (blockIdx.y & (NCOPY - 1)) * CSTRIDE;
#pragma unroll
      for (int j = 0; j < 4; j++) {
        int gc = col0 + cbase + j;
        if (gc < Nc) {
          atomicAdd(&dst[gc], As[0][cbase + j]);
          atomicAdd(&dst[Nc + gc], Ws[0][cbase + j]);
        }
      }
    }
  }
}

// ---------- MFMA f16 GEMM: BM=128 BN=64 BK=32, 4 waves, 2x4 frags of 16x16x32 ----------
// A from fp32 (A) or fp16 (A16). Optional input-BN folded from REPLICATED partials
// (in_part layout: [sum[K], sq[K]] per slot; lives in WORKSPACE, never aliased with
// any output this kernel writes). LDS rows padded to 40 elems.
// C/D layout (m89-verified): col = lane&15, row = (lane>>4)*4 + reg.

__global__ __launch_bounds__(256)
void gemm_mfma_kernel(const float* __restrict__ A, const __half* __restrict__ A16,
                      const float* __restrict__ W,
                      const float* __restrict__ bias, float* __restrict__ C,
                      __half* __restrict__ Ch,
                      const float* __restrict__ in_part, const float* __restrict__ in_g,
                      const float* __restrict__ in_beta, float* __restrict__ out_part,
                      int M, int K, int Nc, int relu) {
  constexpr int BM = 128, BN = 64, BK = 32;
  constexpr int LDA = 40;  // fp16 elems/row incl pad
  __shared__ __half Asm[BM][LDA];
  __shared__ __half Wsm[BN][LDA];     // Wsm[col][k] (transposed tile)
  __shared__ float bnsc[256], bnsh[256];
  __shared__ float sred[2][4][BN];
  int t = threadIdx.x;
  int wid = t >> 6, lane = t & 63;
  int fr = lane & 15, fg = lane >> 4;
  int row0 = blockIdx.y * BM, col0 = blockIdx.x * BN;
  if (in_part) {
    for (int c = t; c < K; c += 256) {
      float s = 0.f, q = 0.f;
#pragma unroll 8
      for (int k = 0; k < NCOPY; k++) {
        s += in_part[k * CSTRIDE + c];
        q += in_part[k * CSTRIDE + K + c];
      }
      float m = s * (1.f / Nn);
      float var = q * (1.f / Nn) - m * m;
      float sc = rsqrtf(var + BN_EPS) * in_g[c];
      bnsc[c] = sc;
      bnsh[c] = in_beta[c] - m * sc;
    }
    __syncthreads();
  }
  f32x4 acc[2][4] = {};
  int ar = t >> 1;             // A stage: row 0..127
  int ac = (t & 1) * 16;       //          k-chunk 0 or 16
  int wc = t >> 2;             // W stage: col 0..63
  int wk = (t & 3) * 8;        //          k-chunk 0/8/16/24
  for (int k0 = 0; k0 < K; k0 += BK) {
    {
      int grow = row0 + ar;
      float v[16];
      if (grow < M) {
        if (A16) {
          union { uint4 u[2]; __half h[16]; } raw;
          const uint4* ap = (const uint4*)(A16 + (size_t)grow * K + k0 + ac);
          raw.u[0] = ap[0]; raw.u[1] = ap[1];
#pragma unroll
          for (int j = 0; j < 16; j++) v[j] = __half2float(raw.h[j]);
        } else {
          const float4* ap = (const float4*)(A + (size_t)grow * K + k0 + ac);
#pragma unroll
          for (int q = 0; q < 4; q++) {
            float4 a = ap[q];
            v[q * 4 + 0] = a.x; v[q * 4 + 1] = a.y;
            v[q * 4 + 2] = a.z; v[q * 4 + 3] = a.w;
          }
        }
        if (in_part) {
#pragma unroll
          for (int j = 0; j < 16; j++)
            v[j] = v[j] * bnsc[k0 + ac + j] + bnsh[k0 + ac + j];
        }
      } else {
#pragma unroll
        for (int j = 0; j < 16; j++) v[j] = 0.f;
      }
      union { __half2 h2[8]; uint4 u4[2]; } pk_;
#pragma unroll
      for (int j = 0; j < 8; j++) pk_.h2[j] = __floats2half2_rn(v[2 * j], v[2 * j + 1]);
      *(uint4*)&Asm[ar][ac] = pk_.u4[0];
      *(uint4*)&Asm[ar][ac + 8] = pk_.u4[1];
    }
    {
      int gc = col0 + wc;
      union { __half2 h2[4]; uint4 u4; } wpk;
#pragma unroll
      for (int j = 0; j < 4; j++) {
        float w0 = W[(size_t)(k0 + wk + 2 * j) * Nc + gc];
        float w1 = W[(size_t)(k0 + wk + 2 * j + 1) * Nc + gc];
        wpk.h2[j] = __floats2half2_rn(w0, w1);
      }
      *(uint4*)&Wsm[wc][wk] = wpk.u4;
    }
    __syncthreads();
    {
      f16x8 a0 = *(const f16x8*)&Asm[wid * 32 + fr][fg * 8];
      f16x8 a1 = *(const f16x8*)&Asm[wid * 32 + 16 + fr][fg * 8];
      f16x8 b0 = *(const f16x8*)&Wsm[fr][fg * 8];
      f16x8 b1 = *(const f16x8*)&Wsm[16 + fr][fg * 8];
      f16x8 b2 = *(const f16x8*)&Wsm[32 + fr][fg * 8];
      f16x8 b3 = *(const f16x8*)&Wsm[48 + fr][fg * 8];
      acc[0][0] = __builtin_amdgcn_mfma_f32_16x16x32_f16(a0, b0, acc[0][0], 0, 0, 0);
      acc[0][1] = __builtin_amdgcn_mfma_f32_16x16x32_f16(a0, b1, acc[0][1], 0, 0, 0);
      acc[0][2] = __builtin_amdgcn_mfma_f32_16x16x32_f16(a0, b2, acc[0][2], 0, 0, 0);
      acc[0][3] = __builtin_amdgcn_mfma_f32_16x16x32_f16(a0, b3, acc[0][3], 0, 0, 0);
      acc[1][0] = __builtin_amdgcn_mfma_f32_16x16x32_f16(a1, b0, acc[1][0], 0, 0, 0);
      acc[1][1] = __builtin_amdgcn_mfma_f32_16x16x32_f16(a1, b1, acc[1][1], 0, 0, 0);
      acc[1][2] = __builtin_amdgcn_mfma_f32_16x16x32_f16(a1, b2, acc[1][2], 0, 0, 0);
      acc[1][3] = __builtin_amdgcn_mfma_f32_16x16x32_f16(a1, b3, acc[1][3], 0, 0, 0);
    }
    __syncthreads();
  }
  // epilogue
  float csum[4] = {}, cssq[4] = {};
  float bv[4];
#pragma unroll
  for (int ni = 0; ni < 4; ni++) bv[ni] = bias ? bias[col0 + ni * 16 + fr] : 0.f;
#pragma unroll
  for (int mi = 0; mi < 2; mi++) {
#pragma unroll
    for (int ni = 0; ni < 4; ni++) {
      int col = col0 + ni * 16 + fr;
      f32x4 d = acc[mi][ni];
#pragma unroll
      for (int j = 0; j < 4; j++) {
        int r = row0 + wid * 32 + mi * 16 + fg * 4 + j;
        if (r >= M) continue;
        float vv = d[j] + bv[ni];
        if (relu) vv = fmaxf(vv, 0.f);
        if (out_part) { csum[ni] += vv; cssq[ni] += vv * vv; }
        if (Ch) Ch[(size_t)r * Nc + col] = __float2half(vv);
        else    C[(size_t)r * Nc + col] = vv;
      }
    }
  }
  if (out_part) {
#pragma unroll
    for (int ni = 0; ni < 4; ni++) {
      csum[ni] += __shfl_xor(csum[ni], 16); csum[ni] += __shfl_xor(csum[ni], 32);
      cssq[ni] += __shfl_xor(cssq[ni], 16); cssq[ni] += __shfl_xor(cssq[ni], 32);
    }
    if (fg == 0) {
#pragma unroll
      for (int ni = 0; ni < 4; ni++) {
        sred[0][wid][ni * 16 + fr] = csum[ni];
        sred[1][wid][ni * 16 + fr] = cssq[ni];
      }
    }
    __syncthreads();
    if (t < BN) {
      float s = sred[0][0][t] + sred[0][1][t] + sred[0][2][t] + sred[0][3][t];
      float q = sred[1][0][t] + sred[1][1][t] + sred[1][2][t] + sred[1][3][t];
      float* dst = out_part + (blockIdx.y & (NCOPY - 1)) * CSTRIDE;
      atomicAdd(&dst[col0 + t], s);
      atomicAdd(&dst[Nc + col0 + t], q);
    }
  }
}

// ---------- gather SpMM (fp16 features, fp32 accumulate) ----------

// 64-dim: 32 lanes per node (half2/lane), 2 nodes per wave, 8 loads in flight
__global__ __launch_bounds__(256)
void gather64_kernel(const __half* __restrict__ t, const int* __restrict__ rowptr,
                     const int2* __restrict__ edge_s,
                     const float* __restrict__ dinv, const float* __restrict__ bias,
                     float* __restrict__ out, __half* __restrict__ outh, int relu) {
  int sub = threadIdx.x >> 5;       // 8 sub-groups of 32 lanes
  int lane = threadIdx.x & 31;
  int node = blockIdx.x * 8 + sub;
  if (node >= Nn) return;
  int start = rowptr[node], end = rowptr[node + 1];
  float s = dinv[node];
  const __half2* tp = (const __half2*)t;  // row stride = 32 half2
  float2 ti = __half22float2(tp[(size_t)node * 32 + lane]);
  float ax = s * s * ti.x, ay = s * s * ti.y;
  for (int base = start; base < end; base += 32) {
    int m = end - base; if (m > 32) m = 32;
    int cv = 0; float nv = 0.f;
    if (lane < m) {
      int2 ev = edge_s[base + lane];
      cv = ev.x; nv = __int_as_float(ev.y);
    }
    int k = 0;
    for (; k + 8 <= m; k += 8) {
      int c0 = __shfl(cv, k + 0, 32), c1 = __shfl(cv, k + 1, 32);
      int c2 = __shfl(cv, k + 2, 32), c3 = __shfl(cv, k + 3, 32);
      int c4 = __shfl(cv, k + 4, 32), c5 = __shfl(cv, k + 5, 32);
      int c6 = __shfl(cv, k + 6, 32), c7 = __shfl(cv, k + 7, 32);
      float n0 = __shfl(nv, k + 0, 32), n1 = __shfl(nv, k + 1, 32);
      float n2 = __shfl(nv, k + 2, 32), n3 = __shfl(nv, k + 3, 32);
      float n4 = __shfl(nv, k + 4, 32), n5 = __shfl(nv, k + 5, 32);
      float n6 = __shfl(nv, k + 6, 32), n7 = __shfl(nv, k + 7, 32);
      float2 t0 = __half22float2(tp[(size_t)c0 * 32 + lane]);
      float2 t1 = __half22float2(tp[(size_t)c1 * 32 + lane]);
      float2 t2 = __half22float2(tp[(size_t)c2 * 32 + lane]);
      float2 t3 = __half22float2(tp[(size_t)c3 * 32 + lane]);
      float2 t4 = __half22float2(tp[(size_t)c4 * 32 + lane]);
      float2 t5 = __half22float2(tp[(size_t)c5 * 32 + lane]);
      float2 t6 = __half22float2(tp[(size_t)c6 * 32 + lane]);
      float2 t7 = __half22float2(tp[(size_t)c7 * 32 + lane]);
      ax += n0 * t0.x; ay += n0 * t0.y;  ax += n1 * t1.x; ay += n1 * t1.y;
      ax += n2 * t2.x; ay += n2 * t2.y;  ax += n3 * t3.x; ay += n3 * t3.y;
      ax += n4 * t4.x; ay += n4 * t4.y;  ax += n5 * t5.x; ay += n5 * t5.y;
      ax += n6 * t6.x; ay += n6 * t6.y;  ax += n7 * t7.x; ay += n7 * t7.y;
    }
    for (; k < m; k++) {
      int c = __shfl(cv, k, 32);
      float nm = __shfl(nv, k, 32);
      float2 tv = __half22float2(tp[(size_t)c * 32 + lane]);
      ax += nm * tv.x; ay += nm * tv.y;
    }
  }
  float2 bb = ((const float2*)bias)[lane];
  ax += bb.x; ay += bb.y;
  if (relu) { ax = fmaxf(ax, 0.f); ay = fmaxf(ay, 0.f); }
  if (outh) ((__half2*)outh)[(size_t)node * 32 + lane] = __floats2half2_rn(ax, ay);
  else      ((float2*)out)[(size_t)node * 32 + lane] = make_float2(ax, ay);
}

// 128-dim: 64 lanes per node (half2/lane), 8 loads in flight, fp16 out
__global__ __launch_bounds__(256)
void gather128_kernel(const __half* __restrict__ t, const int* __restrict__ rowptr,
                      const int2* __restrict__ edge_s,
                      const float* __restrict__ dinv, const float* __restrict__ bias,
                      __half* __restrict__ outh, int relu) {
  int wave = threadIdx.x >> 6;
  int lane = threadIdx.x & 63;
  int node = blockIdx.x * 4 + wave;
  if (node >= Nn) return;
  int start = rowptr[node], end = rowptr[node + 1];
  float s = dinv[node];
  const __half2* tp = (const __half2*)t;  // row stride = 64 half2
  float2 ti = __half22float2(tp[(size_t)node * 64 + lane]);
  float ax = s * s * ti.x, ay = s * s * ti.y;
  for (int base = start; base < end; base += 64) {
    int m = end - base; if (m > 64) m = 64;
    int cv = 0; float nv = 0.f;
    if (lane < m) {
      int2 ev = edge_s[base + lane];
      cv = ev.x; nv = __int_as_float(ev.y);
    }
    int k = 0;
    for (; k + 8 <= m; k += 8) {
      int c0 = __shfl(cv, k + 0), c1 = __shfl(cv, k + 1);
      int c2 = __shfl(cv, k + 2), c3 = __shfl(cv, k + 3);
      int c4 = __shfl(cv, k + 4), c5 = __shfl(cv, k + 5);
      int c6 = __shfl(cv, k + 6), c7 = __shfl(cv, k + 7);
      float n0 = __shfl(nv, k + 0), n1 = __shfl(nv, k + 1);
      float n2 = __shfl(nv, k + 2), n3 = __shfl(nv, k + 3);
      float n4 = __shfl(nv, k + 4), n5 = __shfl(nv, k + 5);
      float n6 = __shfl(nv, k + 6), n7 = __shfl(nv, k + 7);
      float2 t0 = __half22float2(tp[(size_t)c0 * 64 + lane]);
      float2 t1 = __half22float2(tp[(size_t)c1 * 64 + lane]);
      float2 t2 = __half22float2(tp[(size_t)c2 * 64 + lane]);
      float2 t3 = __half22float2(tp[(size_t)c3 * 64 + lane]);
      float2 t4 = __half22float2(tp[(size_t)c4 * 64 + lane]);
      float2 t5 = __half22float2(tp[(size_t)c5 * 64 + lane]);
      float2 t6 = __half22float2(tp[(size_t)c6 * 64 + lane]);
      float2 t7 = __half22float2(tp[(size_t)c7 * 64 + lane]);
      ax += n0 * t0.x; ay += n0 * t0.y;  ax += n1 * t1.x; ay += n1 * t1.y;
      ax += n2 * t2.x; ay += n2 * t2.y;  ax += n3 * t3.x; ay += n3 * t3.y;
      ax += n4 * t4.x; ay += n4 * t4.y;  ax += n5 * t5.x; ay += n5 * t5.y;
      ax += n6 * t6.x; ay += n6 * t6.y;  ax += n7 * t7.x; ay += n7 * t7.y;
    }
    for (; k < m; k++) {
      int c = __shfl(cv, k);
      float nm = __shfl(nv, k);
      float2 tv = __half22float2(tp[(size_t)c * 64 + lane]);
      ax += nm * tv.x; ay += nm * tv.y;
    }
  }
  float2 bb = ((const float2*)bias)[lane];
  ax += bb.x; ay += bb.y;
  if (relu) { ax = fmaxf(ax, 0.f); ay = fmaxf(ay, 0.f); }
  ((__half2*)outh)[(size_t)node * 64 + lane] = __floats2half2_rn(ax, ay);
}

// ---------- fused: mu-BN + z + Student-t q + lv-BN (all stats from partials) ----------

__global__ __launch_bounds__(256)
void q_bn_kernel(const float* __restrict__ mu_raw, const float* __restrict__ part,
                 const float* __restrict__ g_mu, const float* __restrict__ be_mu,
                 const float* __restrict__ g_lv, const float* __restrict__ be_lv,
                 const float* __restrict__ centers,
                 float* __restrict__ out_mu, float* __restrict__ out_z,
                 float* __restrict__ out_lv, float* __restrict__ q) {
  __shared__ float cs[50 * 32];
  __shared__ float cn[50];
  __shared__ float sc[32], sh[32], sc2[32], sh2[32];
  int tid = threadIdx.x;
  for (int i = tid; i < 50 * 32; i += 256) cs[i] = centers[i];
  if (tid < 32) {
    // merged-head stats layout: sums[0..63], sq[64..127]; mu = cols 0..31, lv = 32..63
    float s = 0.f, qq = 0.f, s2 = 0.f, q2 = 0.f;
#pragma unroll 8
    for (int k = 0; k < NCOPY; k++) {
      const float* p = part + k * CSTRIDE;
      s  += p[tid];       qq += p[64 + tid];
      s2 += p[32 + tid];  q2 += p[96 + tid];
    }
    float m = s * (1.f / Nn);
    float var = qq * (1.f / Nn) - m * m;
    float f = rsqrtf(var + BN_EPS) * g_mu[tid];
    sc[tid] = f; sh[tid] = be_mu[tid] - m * f;
    float m2 = s2 * (1.f / Nn);
    float var2 = q2 * (1.f / Nn) - m2 * m2;
    float f2 = rsqrtf(var2 + BN_EPS) * g_lv[tid];
    sc2[tid] = f2; sh2[tid] = be_lv[tid] - m2 * f2;
  }
  __syncthreads();
  if (tid < 50) {
    float s = 0.f;
    for (int j = 0; j < 32; j++) { float v = cs[tid * 32 + j]; s += v * v; }
    cn[tid] = s;
  }
  __syncthreads();
  int n = blockIdx.x * blockDim.x + tid;
  if (n >= Nn) return;
  // lv BN in-place
  {
    float4* lp = (float4*)(out_lv + (size_t)n * 32);
#pragma unroll
    for (int j = 0; j < 8; j++) {
      float4 v = lp[j];
      int c = j * 4;
      v.x = v.x * sc2[c + 0] + sh2[c + 0];
      v.y = v.y * sc2[c + 1] + sh2[c + 1];
      v.z = v.z * sc2[c + 2] + sh2[c + 2];
      v.w = v.w * sc2[c + 3] + sh2[c + 3];
      lp[j] = v;
    }
  }
  float zr[32];
  float zn = 0.f;
  const float4* zp = (const float4*)(mu_raw + (size_t)n * 32);
  float4* mo = (float4*)(out_mu + (size_t)n * 32);
  float4* zo = (float4*)(out_z + (size_t)n * 32);
#pragma unroll
  for (int j = 0; j < 8; j++) {
    float4 v = zp[j];
    int c = j * 4;
    v.x = v.x * sc[c + 0] + sh[c + 0];
    v.y = v.y * sc[c + 1] + sh[c + 1];
    v.z = v.z * sc[c + 2] + sh[c + 2];
    v.w = v.w * sc[c + 3] + sh[c + 3];
    mo[j] = v; zo[j] = v;
    zr[c + 0] = v.x; zr[c + 1] = v.y; zr[c + 2] = v.z; zr[c + 3] = v.w;
    zn += v.x * v.x + v.y * v.y + v.z * v.z + v.w * v.w;
  }
  float qs = 0.f;
  for (int k = 0; k < 50; k++) {
    float dot = 0.f;
#pragma unroll
    for (int j = 0; j < 32; j++) dot += zr[j] * cs[k * 32 + j];
    float d2 = fmaxf(zn + cn[k] - 2.f * dot, 0.f);
    qs += 1.f / (1.f + d2);
  }
  float inv = 1.f / qs;
  float* qo = q + (size_t)n * 50;
  for (int k = 0; k < 50; k++) {
    float dot = 0.f;
#pragma unroll
    for (int j = 0; j < 32; j++) dot += zr[j] * cs[k * 32 + j];
    float d2 = fmaxf(zn + cn[k] - 2.f * dot, 0.f);
    qo[k] = inv / (1.f + d2);
  }
}

// ---------- launch ----------

extern "C" void kernel_launch(void* const* d_in, const int* in_sizes, int n_in,
                              void* d_out, int out_size, void* d_ws, size_t ws_size,
                              hipStream_t stream) {
  const float* x     = (const float*)d_in[0];
  const int*   ei    = (const int*)d_in[1];
  const float* ew    = (const float*)d_in[2];
  const float* W_g1  = (const float*)d_in[3];
  const float* b_g1  = (const float*)d_in[4];
  const float* W_g2  = (const float*)d_in[5];
  const float* b_g2  = (const float*)d_in[6];
  const float* W_g3  = (const float*)d_in[7];
  const float* b_g3  = (const float*)d_in[8];
  const float* W_mu  = (const float*)d_in[9];
  const float* b_mu  = (const float*)d_in[10];
  const float* W_lv  = (const float*)d_in[11];
  const float* b_lv  = (const float*)d_in[12];
  const float* g_mu  = (const float*)d_in[13];
  const float* be_mu = (const float*)d_in[14];
  const float* g_lv  = (const float*)d_in[15];
  const float* be_lv = (const float*)d_in[16];
  const float* W_d1  = (const float*)d_in[17];
  const float* b_d1  = (const float*)d_in[18];
  const float* g_d1  = (const float*)d_in[19];
  const float* be_d1 = (const float*)d_in[20];
  const float* W_d2  = (const float*)d_in[21];
  const float* b_d2  = (const float*)d_in[22];
  const float* g_d2  = (const float*)d_in[23];
  const float* be_d2 = (const float*)d_in[24];
  const float* W_d3  = (const float*)d_in[25];
  const float* b_d3  = (const float*)d_in[26];
  const float* cent  = (const float*)d_in[27];

  const int* row = ei;
  const int* col = ei + Ne;

  float* out    = (float*)d_out;
  float* out_z  = out;
  float* out_mu = out + (size_t)Nn * 32;
  float* out_lv = out + (size_t)Nn * 64;
  float* out_xr = out + (size_t)Nn * 96;   // [N,256]
  float* out_q  = out + (size_t)Nn * 352;  // [N,50]

  // workspace: dinv[N] | bufB[N*128] | wcat[4096] | bcat[64] | stats_part[16K] |
  //            rowptr[N+1] | bsum[129] | edge_s[E int2]   (~64.9 MB)
  float* ws     = (float*)d_ws;
  float* dinv   = ws;
  float* bufB   = dinv + Nn;
  float* wcat   = bufB + (size_t)Nn * 128;
  float* bcat   = wcat + 4096;
  float* stats_part = bcat + 64;                        // NCOPY*CSTRIDE floats, in WS
  int*   rowptr = (int*)(stats_part + NCOPY * CSTRIDE);
  int*   bsum   = rowptr + Nn + 1;
  int2*  edge_s = (int2*)(bsum + 128 + 1);
  unsigned long long* pk = (unsigned long long*)bufB;   // aliased; dead before gather128 writes

  __half* bufB16 = (__half*)bufB;                       // gather128 out / d2 out [N,128] fp16
  __half* tA   = (__half*)out_xr;                       // L1 t [N,128] fp16; L3 t [N,64] fp16
  __half* tC   = (__half*)(out_xr + (size_t)Nn * 128);  // L2 t [N,64] fp16
  float*  bufC = out_xr + (size_t)Nn * 128;             // L3 gather out [N,64] fp32 (tC dead)
  __half* tD   = (__half*)(out_xr + (size_t)Nn * 192);  // gather64-L2 out / d1 out [N,64] fp16
  unsigned short* slot = (unsigned short*)out_q;        // [Ne] u16; dead before q write

  auto cdiv = [](long a, long b) { return (int)((a + b - 1) / b); };
  dim3 blk(256);

  init_kernel<<<cdiv(2L * Nn, 256), blk, 0, stream>>>(
      (int*)pk, stats_part, W_mu, W_lv, b_mu, b_lv, wcat, bcat);
  deg_pack_kernel<<<cdiv(Ne / 4, 256), blk, 0, stream>>>(row, ew, pk, slot);

  scan_phase1<<<SCAN_NB, blk, 0, stream>>>(pk, bsum);
  scan_phase2<<<1, 128, 0, stream>>>(bsum);
  scan_phase3<<<SCAN_NB, blk, 0, stream>>>(pk, bsum, rowptr, dinv);
  csr_fill_kernel<<<cdiv(Ne / 4, 256), blk, 0, stream>>>(row, col, ew, dinv, rowptr, slot, edge_s);

  int g128 = cdiv(Nn, 4);   // gather128: 4 nodes/block
  int g64  = cdiv(Nn, 8);   // gather64: 8 nodes/block
  int gy   = cdiv(Nn, 128); // MFMA rows

  // GCN layer 1: 256 -> 128 (MFMA), aggregate+relu -> fp16
  gemm_mfma_kernel<<<dim3(2, gy), blk, 0, stream>>>(
      x, nullptr, W_g1, nullptr, nullptr, tA, nullptr, nullptr, nullptr, nullptr, Nn, 256, 128, 0);
  gather128_kernel<<<g128, blk, 0, stream>>>(tA, rowptr, edge_s, dinv, b_g1, bufB16, 1);

  // GCN layer 2: 128 -> 64 (MFMA, fp16 A), aggregate+relu -> fp16
  gemm_mfma_kernel<<<dim3(1, gy), blk, 0, stream>>>(
      nullptr, bufB16, W_g2, nullptr, nullptr, tC, nullptr, nullptr, nullptr, nullptr, Nn, 128, 64, 0);
  gather64_kernel<<<g64, blk, 0, stream>>>(tC, rowptr, edge_s, dinv, b_g2, nullptr, tD, 1);

  // GCN layer 3: 64 -> 64 (MFMA, fp16 A), aggregate -> fp32 (feeds fp32 heads)
  gemm_mfma_kernel<<<dim3(1, gy), blk, 0, stream>>>(
      nullptr, tD, W_g3, nullptr, nullptr, tA, nullptr, nullptr, nullptr, nullptr, Nn, 64, 64, 0);
  gather64_kernel<<<g64, blk, 0, stream>>>(tA, rowptr, edge_s, dinv, b_g3, bufC, nullptr, 0);

  // merged VAE heads: 64 -> 64 (cols 0..31 = mu, 32..63 = lv), stats in epilogue
  gemm_kernel<<<dim3(1, cdiv(Nn, 64)), blk, 0, stream>>>(
      bufC, wcat, bcat, out_mu, out_lv, stats_part, Nn, 64, 64, 0);

  // fused mu-BN + z + q + lv-BN (stats folded from partials inline)
  q_bn_kernel<<<cdiv(Nn, 256), blk, 0, stream>>>(out_mu, stats_part, g_mu, be_mu, g_lv, be_lv,
                                                 cent, out_mu, out_z, out_lv, out_q);

  // decoder 32 -> 64 -> 128 -> 256 (MFMA) with BN folded from partials into A-loads
  gemm_mfma_kernel<<<dim3(1, gy), blk, 0, stream>>>(
      out_z, nullptr, W_d1, b_d1, nullptr, tD, nullptr, nullptr, nullptr, stats_part + 128, Nn, 32, 64, 1);
  gemm_mfma_kernel<<<dim3(2, gy), blk, 0, stream>>>(
      nullptr, tD, W_d2, b_d2, nullptr, bufB16, stats_part + 128, g_d1, be_d1, stats_part + 256, Nn, 64, 128, 1);
  gemm_mfma_kernel<<<dim3(4, gy), blk, 0, stream>>>(
      nullptr, bufB16, W_d3, b_d3, out_xr, nullptr, stats_part + 256, g_d2, be_d2, nullptr, Nn, 128, 256, 0);
}